// Round 1
// baseline (587.571 us; speedup 1.0000x reference)
//
#include <hip/hip_runtime.h>

// out[b,o,h,w] = sum_{i,j in 5x5} K[o][i*5+j] * xpad[b, h+i-2, w+j-2] + bias[o]
// K[o][t!=12] = W[o][t<12 ? t : t-1];  K[o][12] = -sum_c W[o][c]
// (collapse of the reference's 24 shift-subtract channels + 1x1 conv)
// K row stride 26: slot 25 holds bias[o] so one scalar-load batch per o.

#define H_DIM 512
#define W_DIM 512
#define BATCH 16
#define OUTC 32
#define KROW 26

#define TILE_W 256
#define TILE_H 8            // 2 rows per thread (BLOCK_Y=4)
#define BLOCK_X 64
#define BLOCK_Y 4
#define HALO_W (TILE_W + 4)   // 260 valid cols
#define LDS_W  (TILE_W + 8)   // 264 stride: keeps every row 16B-aligned
#define LDS_H  (TILE_H + 4)   // 12 rows

__global__ __launch_bounds__(64) void pc_prep(const float* __restrict__ W,
                                              const float* __restrict__ bias,
                                              float* __restrict__ K) {
    int o = threadIdx.x;
    if (o < OUTC) {
        float s = 0.f;
        #pragma unroll
        for (int c = 0; c < 24; ++c) s += W[o * 24 + c];
        #pragma unroll
        for (int t = 0; t < 25; ++t) {
            float v = (t == 12) ? -s : W[o * 24 + (t < 12 ? t : t - 1)];
            K[o * KROW + t] = v;
        }
        K[o * KROW + 25] = bias[o];
    }
}

__global__ __launch_bounds__(256) void pc_conv(const float* __restrict__ x,
                                               const float* __restrict__ K,
                                               float* __restrict__ out) {
    __shared__ float lds[LDS_H * LDS_W];

    const int b  = blockIdx.z;
    const int h0 = blockIdx.y * TILE_H;
    const int w0 = blockIdx.x * TILE_W;
    const int tx = threadIdx.x;            // 0..63
    const int ty = threadIdx.y;            // 0..3

    const float* xb = x + (size_t)b * H_DIM * W_DIM;

    // ---- stage 12 x 260 tile+halo into LDS: division-free, row-coalesced ----
    for (int r = ty; r < LDS_H; r += BLOCK_Y) {          // 3 rows per ty
        const int gh = h0 - 2 + r;
        #pragma unroll
        for (int c0 = 0; c0 < HALO_W; c0 += BLOCK_X) {   // 5 col chunks
            const int c = c0 + tx;
            if (c < HALO_W) {
                const int gw = w0 - 2 + c;
                float v = 0.f;
                if ((unsigned)gh < (unsigned)H_DIM && (unsigned)gw < (unsigned)W_DIM)
                    v = xb[gh * W_DIM + gw];
                lds[r * LDS_W + c] = v;
            }
        }
    }
    __syncthreads();

    // ---- pull this thread's 6x8 neighborhood (2 rows x 4 px) into regs ----
    float nb[6][8];
    #pragma unroll
    for (int r = 0; r < 6; ++r) {
        const float4* p = (const float4*)&lds[(2 * ty + r) * LDS_W + 4 * tx];
        float4 a = p[0];
        float4 c = p[1];
        nb[r][0] = a.x; nb[r][1] = a.y; nb[r][2] = a.z; nb[r][3] = a.w;
        nb[r][4] = c.x; nb[r][5] = c.y; nb[r][6] = c.z; nb[r][7] = c.w;
    }

    const int h = h0 + 2 * ty;
    const int w = w0 + 4 * tx;
    const int rot = blockIdx.y & 31;       // stagger plane order across blocks
    float* obase = out + (size_t)b * OUTC * H_DIM * W_DIM
                       + (size_t)h * W_DIM + w;

    #pragma unroll 2
    for (int oo = 0; oo < OUTC; ++oo) {
        const int o = (oo + rot) & 31;
        const float* kr = K + o * KROW;    // wave-uniform -> scalar loads
        float kk[26];
        #pragma unroll
        for (int t = 0; t < 26; ++t) kk[t] = kr[t];

        const float bb = kk[25];
        float a0 = bb, a1 = bb, a2 = bb, a3 = bb;   // row h
        float b0 = bb, b1 = bb, b2 = bb, b3 = bb;   // row h+1
        #pragma unroll
        for (int ki = 0; ki < 5; ++ki) {
            #pragma unroll
            for (int kj = 0; kj < 5; ++kj) {
                const float k = kk[ki * 5 + kj];
                a0 += k * nb[ki][kj + 0];
                a1 += k * nb[ki][kj + 1];
                a2 += k * nb[ki][kj + 2];
                a3 += k * nb[ki][kj + 3];
                b0 += k * nb[ki + 1][kj + 0];
                b1 += k * nb[ki + 1][kj + 1];
                b2 += k * nb[ki + 1][kj + 2];
                b3 += k * nb[ki + 1][kj + 3];
            }
        }
        float* op = obase + (size_t)o * (H_DIM * W_DIM);
        *(float4*)op            = make_float4(a0, a1, a2, a3);
        *(float4*)(op + W_DIM)  = make_float4(b0, b1, b2, b3);
    }
}

extern "C" void kernel_launch(void* const* d_in, const int* in_sizes, int n_in,
                              void* d_out, int out_size, void* d_ws, size_t ws_size,
                              hipStream_t stream) {
    const float* x    = (const float*)d_in[0];
    const float* W    = (const float*)d_in[1];
    const float* bias = (const float*)d_in[2];
    float* out = (float*)d_out;
    float* K   = (float*)d_ws;   // 32*26 floats = 3328 B

    pc_prep<<<1, 64, 0, stream>>>(W, bias, K);

    dim3 grid(W_DIM / TILE_W, H_DIM / TILE_H, BATCH);   // 2 x 64 x 16
    dim3 block(BLOCK_X, BLOCK_Y, 1);                    // 64 x 4
    pc_conv<<<grid, block, 0, stream>>>(x, K, out);
}